// Round 2
// baseline (1967.282 us; speedup 1.0000x reference)
//
#include <hip/hip_runtime.h>

typedef unsigned short u16;
typedef unsigned int u32;
typedef short short8 __attribute__((ext_vector_type(8)));
typedef float f32x4 __attribute__((ext_vector_type(4)));

#define DEV static __device__ __forceinline__

DEV u16 f2bf(float f) {
  u32 u = __builtin_bit_cast(u32, f);
  u32 r = u + 0x7FFFu + ((u >> 16) & 1u);
  return (u16)(r >> 16);
}
DEV float bf2f(u16 h) { u32 u = ((u32)h) << 16; return __builtin_bit_cast(float, u); }

DEV void async16(const u16* g, u16* l) {
  __builtin_amdgcn_global_load_lds((const __attribute__((address_space(1))) void*)g,
                                   (__attribute__((address_space(3))) void*)l, 16, 0, 0);
}

// ---------------- generic bf16 MFMA GEMM: C = act(A @ Bt^T + bias [+ resid]) ----------
// A: [M][lda] bf16 (dual-source: cols >= KA come from A2), Bt: [N][K] bf16 (pre-transposed W)
// In-place allowed for RESID && !OUTBF with Cf == resid (same-element read-then-write).
template<bool RELU, bool OUTBF, bool RESID>
__global__ __launch_bounds__(256, 2) void gemm_kernel(
    const u16* __restrict__ A, const u16* __restrict__ A2, int KA,
    int lda, int lda2,
    const u16* __restrict__ Bt, int K,
    const float* __restrict__ bias, const float* __restrict__ resid,
    float* __restrict__ Cf, u16* __restrict__ Cb, int N)
{
  __shared__ u16 smem[2][16384];   // [buf][A 8192 | B 8192] = 64 KiB
  const int tid = threadIdx.x, wave = tid >> 6, lane = tid & 63;
  const int m0 = blockIdx.x * 128, n0 = blockIdx.y * 128;
  const int wr = wave >> 1, wc = wave & 1;
  const int lj = lane & 15, hi = lane >> 4;

  f32x4 acc[4][4];
  const f32x4 zz = {0.f, 0.f, 0.f, 0.f};
#pragma unroll
  for (int i = 0; i < 4; i++)
#pragma unroll
    for (int j = 0; j < 4; j++) acc[i][j] = zz;

  const int nkt = K / 64;

  auto stage = [&](int buf, int kt) {
    int kofs = kt * 64;
    const u16* sa; int la;
    if (kofs < KA) { sa = A + kofs; la = lda; }
    else           { sa = A2 + (kofs - KA); la = lda2; }
#pragma unroll
    for (int i = 0; i < 8; i++) {
      int c = wave * 8 + i;
      if (c < 16) {  // A chunk: 8 rows x 64 cols
        const u16* g = sa + (size_t)(m0 + c * 8 + (lane >> 3)) * la + (lane & 7) * 8;
        async16(g, &smem[buf][c * 512]);
      } else {       // B chunk
        const u16* g = Bt + (size_t)(n0 + (c - 16) * 8 + (lane >> 3)) * K + kofs + (lane & 7) * 8;
        async16(g, &smem[buf][c * 512]);
      }
    }
  };

  stage(0, 0);
  int cur = 0;
  for (int kt = 0; kt < nkt; kt++) {
    __syncthreads();                       // drains vmcnt (global_load_lds) + lgkm
    if (kt + 1 < nkt) stage(cur ^ 1, kt + 1);
    const u16* la_ = &smem[cur][0];
    const u16* lb_ = &smem[cur][8192];
#pragma unroll
    for (int ks = 0; ks < 2; ks++) {
      short8 af[4], bfr[4];
#pragma unroll
      for (int mi = 0; mi < 4; mi++)
        af[mi] = *(const short8*)(la_ + (wr * 64 + mi * 16 + lj) * 64 + ks * 32 + hi * 8);
#pragma unroll
      for (int ni = 0; ni < 4; ni++)
        bfr[ni] = *(const short8*)(lb_ + (wc * 64 + ni * 16 + lj) * 64 + ks * 32 + hi * 8);
#pragma unroll
      for (int mi = 0; mi < 4; mi++)
#pragma unroll
        for (int ni = 0; ni < 4; ni++)
          acc[mi][ni] = __builtin_amdgcn_mfma_f32_16x16x32_bf16(af[mi], bfr[ni], acc[mi][ni], 0, 0, 0);
    }
    cur ^= 1;
  }

  float bv[4];
#pragma unroll
  for (int ni = 0; ni < 4; ni++) bv[ni] = bias[n0 + wc * 64 + ni * 16 + lj];
#pragma unroll
  for (int mi = 0; mi < 4; mi++)
#pragma unroll
    for (int r = 0; r < 4; r++) {
      int row = m0 + wr * 64 + mi * 16 + hi * 4 + r;
      size_t rb = (size_t)row * N;
#pragma unroll
      for (int ni = 0; ni < 4; ni++) {
        int col = n0 + wc * 64 + ni * 16 + lj;
        float v = acc[mi][ni][r] + bv[ni];
        if (RESID) v += resid[rb + col];
        if (RELU) v = fmaxf(v, 0.f);
        if (OUTBF) Cb[rb + col] = f2bf(v);
        else Cf[rb + col] = v;
      }
    }
}

// ---------------- AKT attention, one (b, h, q-half of 128) per block ------------------
// Computes S^T = K @ Q^T via MFMA (keys on C-rows -> cumsum is register-local),
// two softmaxes + distance decay in fp32 registers, then O = P @ V via MFMA.
template<bool INCL, bool ZP>
__global__ __launch_bounds__(256, 2) void attn_kernel(
    const u16* __restrict__ qb, const u16* __restrict__ kb, const u16* __restrict__ vb,
    u16* __restrict__ ob, const float* __restrict__ gammas, int li)
{
  __shared__ u16 smem[32768];  // K tile [256][64] @ bytes [0,32768), V^T [64][256] @ [32768,65536)
  const int tid = threadIdx.x, wave = tid >> 6, lane = tid & 63;
  const int qh = blockIdx.x, h = blockIdx.y, b = blockIdx.z;
  const int lj = lane & 15, hi = lane >> 4;
  const size_t rowbase = (size_t)b * 256 * 512 + h * 64;

  // stage K (row-major, XOR-swizzled) and V^T (transposed, XOR-swizzled)
#pragma unroll
  for (int p = 0; p < 8; p++) {
    int r = p * 32 + (tid >> 3);
    int cc = (tid & 7) * 8;
    uint4 kv = *(const uint4*)(kb + rowbase + (size_t)r * 512 + cc);
    *(uint4*)((char*)smem + r * 128 + ((cc * 2) ^ ((r & 7) << 4))) = kv;
    union { uint4 v; u16 e[8]; } uu;
    uu.v = *(const uint4*)(vb + rowbase + (size_t)r * 512 + cc);
#pragma unroll
    for (int i = 0; i < 8; i++) {
      int d = cc + i;
      *(u16*)((char*)smem + 32768 + d * 512 + ((2 * r) ^ ((d & 7) << 4))) = uu.e[i];
    }
  }

  const int qbase = qh * 128 + wave * 32;
  short8 qf[2][2];
#pragma unroll
  for (int cf = 0; cf < 2; cf++)
#pragma unroll
    for (int s = 0; s < 2; s++)
      qf[cf][s] = *(const short8*)(qb + rowbase + (size_t)(qbase + cf * 16 + lj) * 512 + s * 32 + hi * 8);

  float gm = gammas[li * 8 + h];
  float geff = -(gm > 20.f ? gm : log1pf(expf(gm)));   // -softplus(gamma)

  __syncthreads();

  f32x4 acc[16][2];
  const f32x4 zz = {0.f, 0.f, 0.f, 0.f};
#pragma unroll
  for (int rf = 0; rf < 16; rf++) { acc[rf][0] = zz; acc[rf][1] = zz; }

  // QK^T (transposed): acc[rf][cf] holds S^T[key=rf*16+hi*4+r][q=cf*16+lj]
#pragma unroll
  for (int s = 0; s < 2; s++)
#pragma unroll
    for (int rf = 0; rf < 16; rf++) {
      int row = rf * 16 + lj;
      short8 kf = *(const short8*)((char*)smem + row * 128 + ((s * 64 + hi * 16) ^ ((row & 7) << 4)));
      acc[rf][0] = __builtin_amdgcn_mfma_f32_16x16x32_bf16(kf, qf[0][s], acc[rf][0], 0, 0, 0);
      acc[rf][1] = __builtin_amdgcn_mfma_f32_16x16x32_bf16(kf, qf[1][s], acc[rf][1], 0, 0, 0);
    }

  // first softmax stats (scaled by 1/8)
  float m1[2], inv1[2], dtot[2];
#pragma unroll
  for (int cf = 0; cf < 2; cf++) {
    const int q = qbase + cf * 16 + lj;
    float mx = -1e30f;
#pragma unroll
    for (int rf = 0; rf < 16; rf++)
#pragma unroll
      for (int r = 0; r < 4; r++) {
        acc[rf][cf][r] *= 0.125f;
        int k = rf * 16 + hi * 4 + r;
        bool valid = INCL ? (k <= q) : (k < q);
        mx = fmaxf(mx, valid ? acc[rf][cf][r] : -1e30f);
      }
    mx = fmaxf(mx, __shfl_xor(mx, 16));
    mx = fmaxf(mx, __shfl_xor(mx, 32));
    float sum = 0.f;
#pragma unroll
    for (int rf = 0; rf < 16; rf++)
#pragma unroll
      for (int r = 0; r < 4; r++) {
        int k = rf * 16 + hi * 4 + r;
        bool valid = INCL ? (k <= q) : (k < q);
        sum += valid ? expf(acc[rf][cf][r] - mx) : 0.f;
      }
    sum += __shfl_xor(sum, 16);
    sum += __shfl_xor(sum, 32);
    m1[cf] = mx;
    inv1[cf] = sum > 0.f ? 1.f / sum : 0.f;
    dtot[cf] = sum > 0.f ? 1.f : 0.f;   // sum of softmax*mask is exactly 1 (or 0)
  }

  // cumsum of sm over keys -> distance decay -> rescored (in place)
#pragma unroll
  for (int cf = 0; cf < 2; cf++) {
    const int q = qbase + cf * 16 + lj;
    float run = 0.f;
#pragma unroll
    for (int rf = 0; rf < 16; rf++) {
      float p[4];
      float pa = 0.f;
#pragma unroll
      for (int r = 0; r < 4; r++) {
        int k = rf * 16 + hi * 4 + r;
        bool valid = INCL ? (k <= q) : (k < q);
        float smv = valid ? expf(acc[rf][cf][r] - m1[cf]) * inv1[cf] : 0.f;
        pa += smv;
        p[r] = pa;
      }
      float t = p[3];
      float t1 = __shfl_up(t, 16);
      float t2 = __shfl_up(t, 32);
      float t3 = __shfl_up(t, 48);
      float e = (hi >= 1 ? t1 : 0.f) + (hi >= 2 ? t2 : 0.f) + (hi >= 3 ? t3 : 0.f);
      float T = t;
      T += __shfl_xor(T, 16);
      T += __shfl_xor(T, 32);
      float cbase = run + e;
#pragma unroll
      for (int r = 0; r < 4; r++) {
        int k = rf * 16 + hi * 4 + r;
        bool valid = INCL ? (k <= q) : (k < q);
        float tail = fmaxf(dtot[cf] - (cbase + p[r]), 0.f);
        float pos = fabsf((float)(q - k));
        float dist = sqrtf(tail * pos);
        float te = fmaxf(expf(dist * geff), 1e-5f);
        acc[rf][cf][r] = valid ? acc[rf][cf][r] * te : -1e32f;
      }
      run += T;
    }
  }

  // second softmax (normalized P, in place) + zero_pad
#pragma unroll
  for (int cf = 0; cf < 2; cf++) {
    float mx = -3.0e38f;
#pragma unroll
    for (int rf = 0; rf < 16; rf++)
#pragma unroll
      for (int r = 0; r < 4; r++) mx = fmaxf(mx, acc[rf][cf][r]);
    mx = fmaxf(mx, __shfl_xor(mx, 16));
    mx = fmaxf(mx, __shfl_xor(mx, 32));
    float sum = 0.f;
#pragma unroll
    for (int rf = 0; rf < 16; rf++)
#pragma unroll
      for (int r = 0; r < 4; r++) {
        float ev = expf(acc[rf][cf][r] - mx);
        acc[rf][cf][r] = ev;
        sum += ev;
      }
    sum += __shfl_xor(sum, 16);
    sum += __shfl_xor(sum, 32);
    float inv = 1.f / sum;
    if (ZP) { int q = qbase + cf * 16 + lj; if (q == 0) inv = 0.f; }
#pragma unroll
    for (int rf = 0; rf < 16; rf++)
#pragma unroll
      for (int r = 0; r < 4; r++) acc[rf][cf][r] *= inv;
  }

  // PV: O[q][d] = sum_k P[q][k] V[k][d]; A-frags of P repacked in-register via shuffles
  f32x4 oacc[2][4];
#pragma unroll
  for (int i = 0; i < 2; i++)
#pragma unroll
    for (int j = 0; j < 4; j++) oacc[i][j] = zz;

  const int bsrc = lj + 32 * (hi & 1);
  const int hsel = hi >> 1;
#pragma unroll
  for (int sp = 0; sp < 8; sp++) {
    short8 pf[2];
#pragma unroll
    for (int qf2 = 0; qf2 < 2; qf2++) {
      short8 sv;
#pragma unroll
      for (int hh = 0; hh < 2; hh++)
#pragma unroll
        for (int r = 0; r < 4; r++) {
          float va  = __shfl(acc[2 * sp][qf2][r],     bsrc + 16 * hh);
          float vb2 = __shfl(acc[2 * sp + 1][qf2][r], bsrc + 16 * hh);
          sv[hh * 4 + r] = (short)f2bf(hsel ? vb2 : va);
        }
      pf[qf2] = sv;
    }
#pragma unroll
    for (int nf = 0; nf < 4; nf++) {
      int d = nf * 16 + lj;
      short8 vf = *(const short8*)((char*)smem + 32768 + d * 512 + ((sp * 64 + hi * 16) ^ ((d & 7) << 4)));
      oacc[0][nf] = __builtin_amdgcn_mfma_f32_16x16x32_bf16(pf[0], vf, oacc[0][nf], 0, 0, 0);
      oacc[1][nf] = __builtin_amdgcn_mfma_f32_16x16x32_bf16(pf[1], vf, oacc[1][nf], 0, 0, 0);
    }
  }

#pragma unroll
  for (int qf2 = 0; qf2 < 2; qf2++)
#pragma unroll
    for (int r = 0; r < 4; r++) {
      int q = qbase + qf2 * 16 + hi * 4 + r;
      size_t obase = (size_t)(b * 256 + q) * 512 + h * 64;
#pragma unroll
      for (int nf = 0; nf < 4; nf++)
        ob[obase + nf * 16 + lj] = f2bf(oacc[qf2][nf][r]);
    }
}

// ---------------- LayerNorm (row per wave): in-place fp32 + bf16 out ------------------
__global__ __launch_bounds__(256) void ln_kernel(const float* __restrict__ x,
    const float* __restrict__ g, const float* __restrict__ bt,
    float* __restrict__ outF, u16* __restrict__ outB)
{
  int row = blockIdx.x * 4 + (threadIdx.x >> 6), lane = threadIdx.x & 63;
  const float* xr = x + (size_t)row * 512 + lane * 8;
  float4 a = *(const float4*)xr;
  float4 c = *(const float4*)(xr + 4);
  float s = a.x + a.y + a.z + a.w + c.x + c.y + c.z + c.w;
  float q = a.x*a.x + a.y*a.y + a.z*a.z + a.w*a.w + c.x*c.x + c.y*c.y + c.z*c.z + c.w*c.w;
#pragma unroll
  for (int m = 1; m <= 32; m <<= 1) { s += __shfl_xor(s, m); q += __shfl_xor(q, m); }
  float mu = s * (1.f / 512.f);
  float var = q * (1.f / 512.f) - mu * mu;
  float rs = rsqrtf(fmaxf(var, 0.f) + 1e-5f);
  const float* gr = g + lane * 8; const float* br = bt + lane * 8;
  float4 g0 = *(const float4*)gr, g1v = *(const float4*)(gr + 4);
  float4 b0 = *(const float4*)br, b1v = *(const float4*)(br + 4);
  float y[8];
  y[0]=(a.x-mu)*rs*g0.x+b0.x; y[1]=(a.y-mu)*rs*g0.y+b0.y; y[2]=(a.z-mu)*rs*g0.z+b0.z; y[3]=(a.w-mu)*rs*g0.w+b0.w;
  y[4]=(c.x-mu)*rs*g1v.x+b1v.x; y[5]=(c.y-mu)*rs*g1v.y+b1v.y; y[6]=(c.z-mu)*rs*g1v.z+b1v.z; y[7]=(c.w-mu)*rs*g1v.w+b1v.w;
  float* of = outF + (size_t)row * 512 + lane * 8;
  *(float4*)of = make_float4(y[0], y[1], y[2], y[3]);
  *(float4*)(of + 4) = make_float4(y[4], y[5], y[6], y[7]);
  union { uint4 v; u16 e[8]; } pk;
#pragma unroll
  for (int i = 0; i < 8; i++) pk.e[i] = f2bf(y[i]);
  *(uint4*)(outB + (size_t)row * 512 + lane * 8) = pk.v;
}

// ---------------- fp32 -> bf16 convert ------------------------------------------------
__global__ void cvt_kernel(const float* __restrict__ in, u16* __restrict__ out, int n8)
{
  int i = blockIdx.x * 256 + threadIdx.x;
  if (i >= n8) return;
  float4 a = ((const float4*)in)[2 * i], c = ((const float4*)in)[2 * i + 1];
  union { uint4 v; u16 e[8]; } pk;
  pk.e[0]=f2bf(a.x); pk.e[1]=f2bf(a.y); pk.e[2]=f2bf(a.z); pk.e[3]=f2bf(a.w);
  pk.e[4]=f2bf(c.x); pk.e[5]=f2bf(c.y); pk.e[6]=f2bf(c.z); pk.e[7]=f2bf(c.w);
  ((uint4*)out)[i] = pk.v;
}

// ---------------- fp32 [R][C] -> bf16 [C][R] transpose (per-slice z) ------------------
__global__ void trans_kernel(const float* __restrict__ in, u16* __restrict__ out, int R, int C)
{
  __shared__ float tile[32][33];
  size_t off = (size_t)blockIdx.z * R * C;
  in += off; out += off;
  int c0 = blockIdx.x * 32, r0 = blockIdx.y * 32;
  int tx = threadIdx.x & 31, ty = threadIdx.x >> 5;
#pragma unroll
  for (int i = 0; i < 4; i++) tile[ty + i * 8][tx] = in[(size_t)(r0 + ty + i * 8) * C + c0 + tx];
  __syncthreads();
#pragma unroll
  for (int i = 0; i < 4; i++) out[(size_t)(c0 + ty + i * 8) * R + r0 + tx] = f2bf(tile[tx][ty + i * 8]);
}

// ---------------- final: preds = sigmoid(h2 @ O3 + b) ---------------------------------
__global__ __launch_bounds__(256) void pred_kernel(const u16* __restrict__ h2,
    const float* __restrict__ O3, const float* __restrict__ bO3, float* __restrict__ out)
{
  int row = blockIdx.x * 4 + (threadIdx.x >> 6), lane = threadIdx.x & 63;
  union { uint2 v; u16 e[4]; } hv;
  hv.v = *(const uint2*)(h2 + (size_t)row * 256 + lane * 4);
  float d = 0.f;
#pragma unroll
  for (int i = 0; i < 4; i++) d += bf2f(hv.e[i]) * O3[lane * 4 + i];
#pragma unroll
  for (int m = 1; m <= 32; m <<= 1) d += __shfl_xor(d, m);
  if (lane == 0) out[row] = 1.f / (1.f + expf(-(d + bO3[0])));
}

// ======================================================================================
extern "C" void kernel_launch(void* const* d_in, const int* in_sizes, int n_in,
                              void* d_out, int out_size, void* d_ws, size_t ws_size,
                              hipStream_t stream)
{
  const float* qe   = (const float*)d_in[0];
  const float* qa   = (const float*)d_in[1];
  const float* Wq   = (const float*)d_in[2];  const float* bq  = (const float*)d_in[3];
  const float* Wk   = (const float*)d_in[4];  const float* bk  = (const float*)d_in[5];
  const float* Wv   = (const float*)d_in[6];  const float* bv  = (const float*)d_in[7];
  const float* Wo   = (const float*)d_in[8];  const float* bo  = (const float*)d_in[9];
  const float* gam  = (const float*)d_in[10];
  const float* ln1g = (const float*)d_in[11]; const float* ln1b = (const float*)d_in[12];
  const float* W1   = (const float*)d_in[13]; const float* b1  = (const float*)d_in[14];
  const float* W2   = (const float*)d_in[15]; const float* b2  = (const float*)d_in[16];
  const float* ln2g = (const float*)d_in[17]; const float* ln2b = (const float*)d_in[18];
  const float* O1   = (const float*)d_in[19]; const float* bO1 = (const float*)d_in[20];
  const float* O2   = (const float*)d_in[21]; const float* bO2 = (const float*)d_in[22];
  const float* O3   = (const float*)d_in[23]; const float* bO3 = (const float*)d_in[24];
  float* preds = (float*)d_out;

  const int M = 16384;
  const int BIG = 0x3fffffff;
  char* ws = (char*)d_ws;
  size_t off = 0;
  auto alloc = [&](size_t bytes) { char* p = ws + off; off += (bytes + 255) & ~(size_t)255; return p; };

  // ---- compact workspace plan (~190 MB total) ----
  u16* wqt = (u16*)alloc((size_t)6*512*512*2);     // bf16 W^T per layer
  u16* wkt = (u16*)alloc((size_t)6*512*512*2);
  u16* wvt = (u16*)alloc((size_t)6*512*512*2);
  u16* wot = (u16*)alloc((size_t)6*512*512*2);
  u16* w1t = (u16*)alloc((size_t)6*2048*512*2);    // [l][2048][512]
  u16* w2t = (u16*)alloc((size_t)6*512*2048*2);    // [l][512][2048]
  u16* o1t = (u16*)alloc((size_t)512*1024*2);
  u16* o2t = (u16*)alloc((size_t)256*512*2);
  u16* qx  = (u16*)alloc((size_t)M*512*2);         // bf16(q_embed), persists to head
  u16* sA  = (u16*)alloc((size_t)M*512*2);         // stream buf A (ya initially; yfin later)
  u16* sB  = (u16*)alloc((size_t)M*512*2);         // stream buf B
  float* g1 = (float*)alloc((size_t)M*512*4);      // fp32 residual stream (in-place LN)
  u16* region = (u16*)alloc((size_t)M*2048*2);     // qbf|kbf|vbf|obf, aliased by h1
  u16* qbf = region;
  u16* kbf = region + (size_t)M*512;
  u16* vbf = region + (size_t)2*M*512;
  u16* obf = region + (size_t)3*M*512;
  u16* h1  = region;                               // FFN hidden aliases whole region
  u16* hd1 = region;                               // head hidden1 [M][512] (slot 0)
  u16* hd2 = region + (size_t)2*M*512;             // head hidden2 [M][256] (slot 2)
  (void)ws_size; (void)in_sizes; (void)n_in; (void)out_size;

  // weight conversion / transposition (fp32 [K][N] -> bf16 [N][K])
  trans_kernel<<<dim3(16, 16, 6), 256, 0, stream>>>(Wq, wqt, 512, 512);
  trans_kernel<<<dim3(16, 16, 6), 256, 0, stream>>>(Wk, wkt, 512, 512);
  trans_kernel<<<dim3(16, 16, 6), 256, 0, stream>>>(Wv, wvt, 512, 512);
  trans_kernel<<<dim3(16, 16, 6), 256, 0, stream>>>(Wo, wot, 512, 512);
  trans_kernel<<<dim3(64, 16, 6), 256, 0, stream>>>(W1, w1t, 512, 2048);
  trans_kernel<<<dim3(16, 64, 6), 256, 0, stream>>>(W2, w2t, 2048, 512);
  trans_kernel<<<dim3(16, 32, 1), 256, 0, stream>>>(O1, o1t, 1024, 512);
  trans_kernel<<<dim3(8, 16, 1),  256, 0, stream>>>(O2, o2t, 512, 256);
  cvt_kernel<<<4096, 256, 0, stream>>>(qe, qx, M * 512 / 8);
  cvt_kernel<<<4096, 256, 0, stream>>>(qa, sA, M * 512 / 8);

  const u16* curB = sA;
  const float* curF = qa;      // fp32 residual source (input for li=0/2, else g1)
  const u16* yfin = nullptr;
  const dim3 gP(128, 4), gF1(128, 16), gA(2, 8, 64);

  for (int li = 0; li < 6; li++) {
    bool ffn  = (li == 0 || li == 1 || li == 3 || li == 5);
    bool excl = (li == 3 || li == 5);
    const u16* Av = excl ? yfin : curB;
    size_t wo4 = (size_t)li * 512 * 512;

    gemm_kernel<false, true, false><<<gP, 256, 0, stream>>>(curB, curB, BIG, 512, 512, wqt + wo4, 512, bq + li * 512, nullptr, nullptr, qbf, 512);
    gemm_kernel<false, true, false><<<gP, 256, 0, stream>>>(curB, curB, BIG, 512, 512, wkt + wo4, 512, bk + li * 512, nullptr, nullptr, kbf, 512);
    gemm_kernel<false, true, false><<<gP, 256, 0, stream>>>(Av,   Av,   BIG, 512, 512, wvt + wo4, 512, bv + li * 512, nullptr, nullptr, vbf, 512);

    if (!excl) attn_kernel<true,  false><<<gA, 256, 0, stream>>>(qbf, kbf, vbf, obf, gam, li);
    else       attn_kernel<false, true ><<<gA, 256, 0, stream>>>(qbf, kbf, vbf, obf, gam, li);

    // Wo projection + residual -> g1 (in-place safe when curF == g1)
    gemm_kernel<false, false, true><<<gP, 256, 0, stream>>>(obf, obf, BIG, 512, 512, wot + wo4, 512, bo + li * 512, curF, g1, nullptr, 512);

    // LN1: in-place on g1, bf16 copy -> sB (old curB dead: already consumed by Q/K/V gemms)
    ln_kernel<<<4096, 256, 0, stream>>>(g1, ln1g + li * 512, ln1b + li * 512, g1, sB);
    curB = sB; curF = g1;

    if (ffn) {
      gemm_kernel<true, true, false><<<gF1, 256, 0, stream>>>(curB, curB, BIG, 512, 512, w1t + (size_t)li * 2048 * 512, 512, b1 + li * 2048, nullptr, nullptr, h1, 2048);
      gemm_kernel<false, false, true><<<gP, 256, 0, stream>>>(h1, h1, BIG, 2048, 2048, w2t + (size_t)li * 512 * 2048, 2048, b2 + li * 512, g1, g1, nullptr, 512);
      u16* nB = (li < 2) ? sA : sB;    // y-stream parks in sA (yfin); x-stream stays on sB
      ln_kernel<<<4096, 256, 0, stream>>>(g1, ln2g + li * 512, ln2b + li * 512, g1, nB);
      curB = nB;
    }
    if (li == 1) { yfin = curB; curB = qx; curF = qe; }
  }

  // final head: concat([x, q_embed]) @ O1 (dual-source K=1024) -> relu -> O2 -> relu -> O3 -> sigmoid
  gemm_kernel<true, true, false><<<dim3(128, 4), 256, 0, stream>>>(curB, qx, 512, 512, 512, o1t, 1024, bO1, nullptr, nullptr, hd1, 512);
  gemm_kernel<true, true, false><<<dim3(128, 2), 256, 0, stream>>>(hd1, hd1, BIG, 512, 512, o2t, 512, bO2, nullptr, nullptr, hd2, 256);
  pred_kernel<<<4096, 256, 0, stream>>>(hd2, O3, bO3, preds);
}